// Round 4
// baseline (1607.009 us; speedup 1.0000x reference)
//
#include <hip/hip_runtime.h>
#include <hip/hip_bf16.h>
#include <cmath>

typedef __bf16 bf16x8 __attribute__((ext_vector_type(8)));
typedef unsigned short u16x8_t __attribute__((ext_vector_type(8)));
typedef float f32x4 __attribute__((ext_vector_type(4)));
typedef unsigned short u16;

__device__ inline bf16x8 ld16(const void* p) {
  return __builtin_bit_cast(bf16x8, *reinterpret_cast<const u16x8_t*>(p));
}
__device__ inline void async16(const void* g, void* l) {
  __builtin_amdgcn_global_load_lds(
      (const __attribute__((address_space(1))) unsigned int*)g,
      (__attribute__((address_space(3))) unsigned int*)l, 16, 0, 0);
}
__device__ inline u16 f2bf(float v) {
  return __builtin_bit_cast(u16, __float2bfloat16(v));
}
__device__ inline float bf2f(u16 v) {
  unsigned int u = ((unsigned int)v) << 16;
  return __builtin_bit_cast(float, u);
}
// barrier with LDS-visibility only (no vmcnt drain -> keeps prefetch in flight)
__device__ inline void bar_lds() {
  asm volatile("s_waitcnt lgkmcnt(0)" ::: "memory");
  __builtin_amdgcn_sched_barrier(0);
  __builtin_amdgcn_s_barrier();
}
// full barrier (stage loads + LDS)
__device__ inline void bar_all() {
  asm volatile("s_waitcnt vmcnt(0) lgkmcnt(0)" ::: "memory");
  __builtin_amdgcn_sched_barrier(0);
  __builtin_amdgcn_s_barrier();
}

// ---------------- cast f32 -> bf16 (vectorized, zero-pad past nsrc) ----------
__global__ void cast4(const float* __restrict__ src, u16* __restrict__ dst,
                      long n, long nsrc) {
  for (long i = (long)blockIdx.x * 256 + threadIdx.x; i * 4 < n;
       i += (long)gridDim.x * 256) {
    float4 v;
    if (i * 4 < nsrc) v = ((const float4*)src)[i];
    else { v.x = v.y = v.z = v.w = 0.f; }
    ushort4 o;
    o.x = f2bf(v.x); o.y = f2bf(v.y); o.z = f2bf(v.z); o.w = f2bf(v.w);
    ((ushort4*)dst)[i] = o;
  }
}

__global__ void fill_dbg(float* __restrict__ out, long n, float v) {
  for (long i = (long)blockIdx.x * 256 + threadIdx.x; i < n;
       i += (long)gridDim.x * 256) out[i] = v;
}

// ---------------- wkv_b -> per-head transposed nope part + v part ------------
__global__ void prep_wkvb(const float* __restrict__ in, u16* __restrict__ outT,
                          u16* __restrict__ outV) {
  int h = blockIdx.x >> 7, d = blockIdx.x & 127;
  const float* r0 = in + (long)(h * 256 + d) * 512;
  const float* r1 = in + (long)(h * 256 + 128 + d) * 512;
  for (int c = threadIdx.x; c < 512; c += 256) {
    outT[((long)h * 512 + c) * 128 + d] = f2bf(r0[c]);
    outV[((long)h * 128 + d) * 512 + c] = f2bf(r1[c]);
  }
}

// ---------------- generic C = A * B^T bf16 GEMM (m97 structure) --------------
template <bool OUT_BF16>
__global__ __launch_bounds__(256) void gemm_bt(
    const u16* __restrict__ A, long lda,
    const u16* __restrict__ B, long ldb,
    void* __restrict__ Cv, long ldc, int K) {
  const long m0 = (long)blockIdx.y * 128, n0 = (long)blockIdx.x * 128;
  __shared__ __align__(16) u16 As[128][32];
  __shared__ __align__(16) u16 Bs[128][32];
  const int tid = threadIdx.x, lane = tid & 63, wv = tid >> 6;
  const int wm = (wv >> 1) * 64, wn = (wv & 1) * 64;
  const int lr = lane & 15, lg = lane >> 4;
  f32x4 acc[4][4];
#pragma unroll
  for (int i = 0; i < 4; i++)
#pragma unroll
    for (int j = 0; j < 4; j++) acc[i][j] = f32x4{0.f, 0.f, 0.f, 0.f};
  const int rr = tid >> 2, ko = (tid & 3) * 8;
  for (int k0 = 0; k0 < K; k0 += 32) {
    __syncthreads();
    async16(A + (m0 + rr) * lda + k0 + ko, &As[rr][ko]);
    async16(A + (m0 + rr + 64) * lda + k0 + ko, &As[rr + 64][ko]);
    async16(B + (n0 + rr) * ldb + k0 + ko, &Bs[rr][ko]);
    async16(B + (n0 + rr + 64) * ldb + k0 + ko, &Bs[rr + 64][ko]);
    __syncthreads();
    bf16x8 af[4], bfr[4];
#pragma unroll
    for (int mi = 0; mi < 4; mi++) af[mi] = ld16(&As[wm + mi * 16 + lr][lg * 8]);
#pragma unroll
    for (int ni = 0; ni < 4; ni++) bfr[ni] = ld16(&Bs[wn + ni * 16 + lr][lg * 8]);
#pragma unroll
    for (int mi = 0; mi < 4; mi++)
#pragma unroll
      for (int ni = 0; ni < 4; ni++)
        acc[mi][ni] = __builtin_amdgcn_mfma_f32_16x16x32_bf16(
            af[mi], bfr[ni], acc[mi][ni], 0, 0, 0);
  }
#pragma unroll
  for (int mi = 0; mi < 4; mi++)
#pragma unroll
    for (int ni = 0; ni < 4; ni++)
#pragma unroll
      for (int j = 0; j < 4; j++) {
        long row = m0 + wm + mi * 16 + lg * 4 + j;
        long col = n0 + wn + ni * 16 + lr;
        long idx = row * ldc + col;
        if (OUT_BF16) ((u16*)Cv)[idx] = f2bf(acc[mi][ni][j]);
        else ((float*)Cv)[idx] = acc[mi][ni][j];
      }
}

// ---------------- q fixup: split nope/pe, RoPE pe (bf16 in) ------------------
__global__ void fixup_q(const u16* __restrict__ q, const float* __restrict__ freqs,
                        u16* __restrict__ qn, u16* __restrict__ qpe) {
  long row = blockIdx.x;
  int s = (int)(row & 2047);
  const u16* qr = q + row * 3072;
  for (int j = threadIdx.x; j < 2048; j += 256) {
    int h = j >> 7, d = j & 127;
    qn[row * 2048 + j] = qr[h * 192 + d];
  }
  for (int j = threadIdx.x; j < 1024; j += 256) {
    int h = j >> 6, t = j & 63, p = t >> 1;
    float ang = freqs[s * 32 + p];
    float co = cosf(ang), sn = sinf(ang);
    float x0 = bf2f(qr[h * 192 + 128 + 2 * p]);
    float x1 = bf2f(qr[h * 192 + 128 + 2 * p + 1]);
    float y = (t & 1) ? (x0 * sn + x1 * co) : (x0 * co - x1 * sn);
    qpe[row * 1024 + j] = f2bf(y);
  }
}

// ---------------- kv fixup: RMSNorm(kv)*w -> bf16, RoPE(k_pe) -> bf16 --------
__global__ void fixup_kv(const float* __restrict__ kvf, const float* __restrict__ w,
                         const float* __restrict__ freqs, u16* __restrict__ kvn,
                         u16* __restrict__ kpe) {
  long row = blockIdx.x;
  int s = (int)(row & 2047);
  const float* src = kvf + row * 640;
  int t = threadIdx.x;
  float x0 = src[t], x1 = src[t + 256];
  float ss = x0 * x0 + x1 * x1;
  for (int d = 1; d < 64; d <<= 1) ss += __shfl_xor(ss, d);
  __shared__ float wsum[4];
  if ((t & 63) == 0) wsum[t >> 6] = ss;
  __syncthreads();
  float tot = wsum[0] + wsum[1] + wsum[2] + wsum[3];
  float inv = rsqrtf(tot * (1.0f / 512.0f) + 1e-6f);
  kvn[row * 512 + t] = f2bf(x0 * inv * w[t]);
  kvn[row * 512 + t + 256] = f2bf(x1 * inv * w[t + 256]);
  if (t < 64) {
    int p = t >> 1;
    float ang = freqs[s * 32 + p];
    float co = cosf(ang), sn = sinf(ang);
    float a0 = src[512 + 2 * p], a1 = src[512 + 2 * p + 1];
    float y = (t & 1) ? (a0 * sn + a1 * co) : (a0 * co - a1 * sn);
    kpe[row * 64 + t] = f2bf(y);
  }
}

// ---------------- kvn [4096][512] -> kvt [2][512][2048] (per-batch T) --------
__global__ void transpose_kv(const u16* __restrict__ kvn, u16* __restrict__ kvt) {
  __shared__ u16 T[32][33];
  int b = blockIdx.z;
  int s0 = blockIdx.x * 32, c0 = blockIdx.y * 32;
  int r = threadIdx.x >> 5, c = threadIdx.x & 31;
  for (int rr = r; rr < 32; rr += 8)
    T[rr][c] = kvn[((long)b * 2048 + s0 + rr) * 512 + c0 + c];
  __syncthreads();
  for (int rr = r; rr < 32; rr += 8)
    kvt[((long)b * 512 + c0 + rr) * 2048 + s0 + c] = T[c][rr];
}

// ---------------- fused flash MLA attention (QBLK=64, KVBLK=32, K-dbuf) ------
// 8 waves. Score role: wave=(rg 0..3 rows rg*16, cp 0..1 cols cp*16), 18 MFMA.
// O role: wave=(qg 0..1 rows qg*32, cg 0..3 cols cg*128), 16 MFMA.
// Q_abs persistent in LDS (computed in P1); K double-buffered via
// global_load_lds; V and k_pe direct global->register; softmax running state
// (Mrun) double-buffered in LDS. 3 barriers/tile, vmcnt(0) only at tile end.
__device__ inline int qswz(int row, int col) {  // [64][512] u16 tile
  return row * 512 + ((((col >> 3) ^ (row & 7)) << 3) | (col & 7));
}

__global__ __launch_bounds__(512, 2) void mla_flash(
    const u16* __restrict__ qn, const u16* __restrict__ qpe,
    const u16* __restrict__ wbT, const u16* __restrict__ wbV,
    const u16* __restrict__ kvn, const u16* __restrict__ kpe,
    const u16* __restrict__ kvt, u16* __restrict__ ov, float scale) {
  __shared__ __align__(16) u16 Qs[64 * 512];     // 64KB, qswz
  __shared__ __align__(16) u16 Ks[2][32 * 512];  // 2x32KB, chunk^(r&7)
  __shared__ __align__(16) u16 Psh[64 * 32];     // 4KB, chunk^(r&3)
  __shared__ float Msh[64][2];
  __shared__ float Lsh[64][2];
  __shared__ float Mrun[2][64];

  const int qb = (31 - (int)blockIdx.x) * 64;  // longest first
  const int h = blockIdx.y, b = blockIdx.z;
  const int tid = threadIdx.x, lane = tid & 63, wv = tid >> 6;
  const int lr = lane & 15, lg = lane >> 4;
  const int rg = wv & 3, cp = wv >> 2;   // score role
  const int qg = wv & 1, cg = wv >> 1;   // O role
  const int rloc = rg * 16 + lg * 4;     // score D-frag row base

  // ---- P1: q_abs (64x512, K=128) -> Qs; init Mrun ----
  if (tid < 64) Mrun[0][tid] = -INFINITY;
  {
    const int pr = rg, pc = cp;  // rows pr*16, cols pc*256
    const u16* aqp =
        qn + ((long)b * 2048 + qb + pr * 16 + lr) * 2048 + h * 128 + lg * 8;
    bf16x8 aq[4];
#pragma unroll
    for (int ks = 0; ks < 4; ks++) aq[ks] = ld16(aqp + ks * 32);
#pragma unroll
    for (int ni = 0; ni < 16; ni++) {
      f32x4 acc = f32x4{0.f, 0.f, 0.f, 0.f};
#pragma unroll
      for (int ks = 0; ks < 4; ks++) {
        bf16x8 bw = ld16(wbT + ((long)h * 512 + pc * 256 + ni * 16 + lr) * 128 +
                         ks * 32 + lg * 8);
        acc = __builtin_amdgcn_mfma_f32_16x16x32_bf16(aq[ks], bw, acc, 0, 0, 0);
      }
#pragma unroll
      for (int j = 0; j < 4; j++)
        Qs[qswz(pr * 16 + lg * 4 + j, pc * 256 + ni * 16 + lr)] = f2bf(acc[j]);
    }
  }
  // q_pe A-frags (score role), persistent
  bf16x8 qpf0, qpf1;
  {
    const u16* qpp =
        qpe + ((long)b * 2048 + qb + rg * 16 + lr) * 1024 + h * 64 + lg * 8;
    qpf0 = ld16(qpp);
    qpf1 = ld16(qpp + 32);
  }

  f32x4 O[2][8];
  float lrow[2][4];
#pragma unroll
  for (int rb = 0; rb < 2; rb++) {
#pragma unroll
    for (int ni = 0; ni < 8; ni++) O[rb][ni] = f32x4{0.f, 0.f, 0.f, 0.f};
#pragma unroll
    for (int j = 0; j < 4; j++) lrow[rb][j] = 0.f;
  }

  auto stageK = [&](int t, int buf) {
    const int tb = t * 32;
#pragma unroll
    for (int it = 0; it < 4; it++) {
      int c = tid + it * 512;
      int r = c >> 6, o = c & 63;
      int og = o ^ (r & 7);
      const u16* src = kvn + ((long)b * 2048 + tb + r) * 512 + og * 8;
      async16(src, ((char*)Ks[buf]) + (long)c * 16);
    }
  };

  stageK(0, 0);
  bar_all();  // Qs visible + K[0] staged

  const int nt = qb / 32 + 2;
  for (int t = 0; t < nt; t++) {
    const int cur = t & 1;
    const int tb = t * 32;
    if (t + 1 < nt) stageK(t + 1, cur ^ 1);
    // V B-frags direct from global (O role)
    bf16x8 vf[8];
#pragma unroll
    for (int ni = 0; ni < 8; ni++)
      vf[ni] = ld16(kvt + ((long)b * 512 + cg * 128 + ni * 16 + lr) * 2048 + tb +
                    lg * 8);
    // k_pe B-frags direct from global (score role)
    const u16* kpp = kpe + ((long)b * 2048 + tb + cp * 16 + lr) * 64 + lg * 8;
    bf16x8 kp0 = ld16(kpp), kp1 = ld16(kpp + 32);

    // ---- phase 1: QK ----
    f32x4 a0 = f32x4{0.f, 0.f, 0.f, 0.f}, a1 = f32x4{0.f, 0.f, 0.f, 0.f};
    {
      const int qrow = rg * 16 + lr, krow = cp * 16 + lr;
      const u16* kb = Ks[cur];
#pragma unroll
      for (int f = 0; f < 8; f++) {
        bf16x8 q0 = ld16(&Qs[qswz(qrow, (2 * f) * 32 + lg * 8)]);
        bf16x8 k0 = ld16(&kb[krow * 512 +
                             ((((2 * f) * 4 + lg) ^ (krow & 7)) << 3)]);
        a0 = __builtin_amdgcn_mfma_f32_16x16x32_bf16(q0, k0, a0, 0, 0, 0);
        bf16x8 q1 = ld16(&Qs[qswz(qrow, (2 * f + 1) * 32 + lg * 8)]);
        bf16x8 k1 = ld16(&kb[krow * 512 +
                             ((((2 * f + 1) * 4 + lg) ^ (krow & 7)) << 3)]);
        a1 = __builtin_amdgcn_mfma_f32_16x16x32_bf16(q1, k1, a1, 0, 0, 0);
      }
      a0 = __builtin_amdgcn_mfma_f32_16x16x32_bf16(qpf0, kp0, a0, 0, 0, 0);
      a1 = __builtin_amdgcn_mfma_f32_16x16x32_bf16(qpf1, kp1, a1, 0, 0, 0);
    }
    float s4[4], mt[4];
#pragma unroll
    for (int j = 0; j < 4; j++) {
      int grow = qb + rloc + j, col = tb + cp * 16 + lr;
      float sv = (a0[j] + a1[j]) * scale;
      s4[j] = (col <= grow) ? sv : -INFINITY;
      mt[j] = s4[j];
    }
#pragma unroll
    for (int d = 1; d < 16; d <<= 1)
#pragma unroll
      for (int j = 0; j < 4; j++) mt[j] = fmaxf(mt[j], __shfl_xor(mt[j], d));
    if (lr == 0)
#pragma unroll
      for (int j = 0; j < 4; j++) Msh[rloc + j][cp] = mt[j];
    bar_lds();  // B-M

    // ---- phase 2: softmax ----
    float p4[4], ls[4], mnS[4];
#pragma unroll
    for (int j = 0; j < 4; j++) {
      int row = rloc + j;
      float mn = fmaxf(fmaxf(Msh[row][0], Msh[row][1]), Mrun[cur][row]);
      mnS[j] = mn;
      p4[j] = __expf(s4[j] - mn);
      ls[j] = p4[j];
    }
#pragma unroll
    for (int d = 1; d < 16; d <<= 1)
#pragma unroll
      for (int j = 0; j < 4; j++) ls[j] += __shfl_xor(ls[j], d);
    if (lr == 0)
#pragma unroll
      for (int j = 0; j < 4; j++) Lsh[rloc + j][cp] = ls[j];
    if (cp == 0 && lr == 0)
#pragma unroll
      for (int j = 0; j < 4; j++) Mrun[cur ^ 1][rloc + j] = mnS[j];
#pragma unroll
    for (int j = 0; j < 4; j++) {
      int row = rloc + j;
      int cx = ((cp * 2 + (lr >> 3)) ^ (row & 3));
      Psh[row * 32 + (cx << 3) + (lr & 7)] = f2bf(p4[j]);
    }
    // O rescale (O role)
    float fac[2][4];
#pragma unroll
    for (int rb = 0; rb < 2; rb++)
#pragma unroll
      for (int j = 0; j < 4; j++) {
        int row = qg * 32 + rb * 16 + lg * 4 + j;
        float mp = Mrun[cur][row];
        float mn = fmaxf(fmaxf(Msh[row][0], Msh[row][1]), mp);
        fac[rb][j] = __expf(mp - mn);
      }
#pragma unroll
    for (int rb = 0; rb < 2; rb++)
#pragma unroll
      for (int ni = 0; ni < 8; ni++)
#pragma unroll
        for (int j = 0; j < 4; j++) O[rb][ni][j] *= fac[rb][j];
    bar_lds();  // B-P

    // ---- phase 3: l update + PV ----
#pragma unroll
    for (int rb = 0; rb < 2; rb++)
#pragma unroll
      for (int j = 0; j < 4; j++) {
        int row = qg * 32 + rb * 16 + lg * 4 + j;
        lrow[rb][j] = lrow[rb][j] * fac[rb][j] + Lsh[row][0] + Lsh[row][1];
      }
    bf16x8 pf[2];
#pragma unroll
    for (int rb = 0; rb < 2; rb++) {
      int prow = qg * 32 + rb * 16 + lr;
      pf[rb] = ld16(&Psh[prow * 32 + ((lg ^ (prow & 3)) << 3)]);
    }
#pragma unroll
    for (int rb = 0; rb < 2; rb++)
#pragma unroll
      for (int ni = 0; ni < 8; ni++)
        O[rb][ni] =
            __builtin_amdgcn_mfma_f32_16x16x32_bf16(pf[rb], vf[ni], O[rb][ni], 0, 0, 0);
    bar_all();  // B-end: K[t+1] staged by all waves
  }

  // ---- P4: normalized O -> Qs (reuse), then ov = O @ wbV[h]^T ----
#pragma unroll
  for (int rb = 0; rb < 2; rb++) {
    float inv[4];
#pragma unroll
    for (int j = 0; j < 4; j++) inv[j] = 1.0f / lrow[rb][j];
#pragma unroll
    for (int ni = 0; ni < 8; ni++)
#pragma unroll
      for (int j = 0; j < 4; j++)
        Qs[qswz(qg * 32 + rb * 16 + lg * 4 + j, cg * 128 + ni * 16 + lr)] =
            f2bf(O[rb][ni][j] * inv[j]);
  }
  bar_lds();
  {
    const int er = rg, ec = cp;  // rows er*16, cols ec*64
    f32x4 vacc[4];
#pragma unroll
    for (int ni = 0; ni < 4; ni++) vacc[ni] = f32x4{0.f, 0.f, 0.f, 0.f};
#pragma unroll
    for (int ks = 0; ks < 16; ks++) {
      bf16x8 ao = ld16(&Qs[qswz(er * 16 + lr, ks * 32 + lg * 8)]);
#pragma unroll
      for (int ni = 0; ni < 4; ni++) {
        bf16x8 bw = ld16(wbV + ((long)h * 128 + ec * 64 + ni * 16 + lr) * 512 +
                         ks * 32 + lg * 8);
        vacc[ni] = __builtin_amdgcn_mfma_f32_16x16x32_bf16(ao, bw, vacc[ni], 0, 0, 0);
      }
    }
#pragma unroll
    for (int ni = 0; ni < 4; ni++)
#pragma unroll
      for (int j = 0; j < 4; j++)
        ov[((long)b * 2048 + qb + er * 16 + lg * 4 + j) * 2048 + h * 128 +
           ec * 64 + ni * 16 + lr] = f2bf(vacc[ni][j]);
  }
}

// =============================================================================
extern "C" void kernel_launch(void* const* d_in, const int* in_sizes, int n_in,
                              void* d_out, int out_size, void* d_ws, size_t ws_size,
                              hipStream_t stream) {
  const float* x     = (const float*)d_in[0];
  const float* wq    = (const float*)d_in[1];
  const float* wkva  = (const float*)d_in[2];
  const float* knw   = (const float*)d_in[3];
  const float* wkvb  = (const float*)d_in[4];
  const float* wo    = (const float*)d_in[5];
  const float* freqs = (const float*)d_in[6];
  float* out = (float*)d_out;

  char* ws = (char*)d_ws;
  size_t off = 0;
  auto alloc = [&](size_t bytes) {
    char* p = ws + off;
    off += (bytes + 255) & ~(size_t)255;
    return p;
  };
  u16* qn    = (u16*)alloc(8388608ull * 2);   // [4096][16][128]
  u16* xb    = (u16*)alloc(8388608ull * 2);   // [4096][2048]
  u16* wqb   = (u16*)alloc(6291456ull * 2);   // [3072][2048]
  u16* wkvab = (u16*)alloc(1310720ull * 2);   // [640][2048] (rows >=576 zero)
  float* kvf = (float*)alloc(2621440ull * 4); // [4096][640]
  u16* wbT   = (u16*)alloc(1048576ull * 2);   // [16][512][128]
  u16* wbV   = (u16*)alloc(1048576ull * 2);   // [16][128][512]
  u16* wob   = (u16*)alloc(4194304ull * 2);   // [2048][2048]
  u16* qpe_  = (u16*)alloc(4194304ull * 2);   // [4096][16][64]
  u16* kvn   = (u16*)alloc(2097152ull * 2);   // [4096][512]
  u16* kpe   = (u16*)alloc(262144ull * 2);    // [4096][64]
  u16* kvt   = (u16*)alloc(2097152ull * 2);   // [2][512][2048]
  u16* ovb   = (u16*)alloc(8388608ull * 2);   // [4096][2048]
  u16* qbig = (u16*)d_out;  // bf16 [4096][3072] in d_out, dead before final GEMM

  if (off > ws_size) {
    fill_dbg<<<2048, 256, 0, stream>>>(out, 8388608L, (float)(ws_size >> 20));
    return;
  }

  double msc = 0.1 * log(40.0) + 1.0;
  float scale = (float)(pow(192.0, -0.5) * msc * msc);

  cast4<<<1024, 256, 0, stream>>>(x, xb, 8388608L, 8388608L);
  cast4<<<1024, 256, 0, stream>>>(wq, wqb, 6291456L, 6291456L);
  cast4<<<1024, 256, 0, stream>>>(wkva, wkvab, 1310720L, 1179648L);
  cast4<<<1024, 256, 0, stream>>>(wo, wob, 4194304L, 4194304L);
  prep_wkvb<<<2048, 256, 0, stream>>>(wkvb, wbT, wbV);

  gemm_bt<true><<<dim3(24, 32, 1), 256, 0, stream>>>(
      xb, 2048, wqb, 2048, qbig, 3072, 2048);
  gemm_bt<false><<<dim3(5, 32, 1), 256, 0, stream>>>(
      xb, 2048, wkvab, 2048, kvf, 640, 2048);

  fixup_q<<<4096, 256, 0, stream>>>(qbig, freqs, qn, qpe_);
  fixup_kv<<<4096, 256, 0, stream>>>(kvf, knw, freqs, kvn, kpe);
  transpose_kv<<<dim3(64, 16, 2), 256, 0, stream>>>(kvn, kvt);

  mla_flash<<<dim3(32, 16, 2), 512, 0, stream>>>(qn, qpe_, wbT, wbV, kvn, kpe,
                                                 kvt, ovb, scale);

  gemm_bt<false><<<dim3(16, 32, 1), 256, 0, stream>>>(
      ovb, 2048, wob, 2048, out, 2048, 2048);
}